// Round 6
// baseline (452.513 us; speedup 1.0000x reference)
//
#include <hip/hip_runtime.h>
#include <hip/hip_bf16.h>
#include <cstdint>

// Problem constants: B=4, N=1024, F=1024, H=16, D=64, S=2N=2048.
typedef __hip_bfloat16 bf16;
typedef __attribute__((ext_vector_type(8))) short short8;   // 8 x bf16 (4 VGPRs)
typedef __attribute__((ext_vector_type(4))) float f32x4;

#define MFMA16(a, b, c) __builtin_amdgcn_mfma_f32_16x16x32_bf16((a), (b), (c), 0, 0, 0)

__device__ __forceinline__ void gl2lds16(const void* g, void* l) {
  // async global->LDS, 16B/lane; LDS dest = wave-uniform base + lane*16
  __builtin_amdgcn_global_load_lds(
      (const __attribute__((address_space(1))) unsigned int*)g,
      (__attribute__((address_space(3))) unsigned int*)l,
      16, 0, 0);
}

// pack two f32 -> bf16x2, round-half-up (3 VALU: add, add, v_perm)
__device__ __forceinline__ unsigned int pkbf(float a, float b) {
  const unsigned int ua = __builtin_bit_cast(unsigned int, a) + 0x8000u;
  const unsigned int ub = __builtin_bit_cast(unsigned int, b) + 0x8000u;
  return __builtin_amdgcn_perm(ub, ua, 0x07060302u);  // {hi16(ua), hi16(ub)<<16}
}
// truncating pack (1 VALU op). p>=0 and l stays exact fp32, so the <=0.4%
// downward bias on P is far inside the bf16 threshold.
__device__ __forceinline__ unsigned int pkbf_t(float a, float b) {
  return __builtin_amdgcn_perm(__builtin_bit_cast(unsigned int, b),
                               __builtin_bit_cast(unsigned int, a), 0x07060302u);
}

// ---------------------------------------------------------------------------
// C[M,N] = A[M,K] @ Bt[N,K]^T + bias   (all bf16 in, fp32 accum)
// 128x128 tile, BK=32, 256 threads (4 waves in 2x2), 16x16x32 bf16 MFMA.
// ---------------------------------------------------------------------------
template <int WRITE_BF16>
__global__ __launch_bounds__(256) void gemm_bt(
    const bf16* __restrict__ A, const bf16* __restrict__ Bt,
    const float* __restrict__ bias, bf16* __restrict__ outb,
    float* __restrict__ outf, int M, int N, int K) {
  __shared__ bf16 sA[128 * 32];
  __shared__ bf16 sB[128 * 32];
  const int tid = threadIdx.x, w = tid >> 6, lane = tid & 63;
  const int n16 = lane & 15, quad = lane >> 4;
  const int mBase = blockIdx.y * 128, nBase = blockIdx.x * 128;
  const int wr = w >> 1, wc = w & 1;  // wave covers rows wr*64.., cols wc*64..

  f32x4 acc[4][4];
#pragma unroll
  for (int mi = 0; mi < 4; mi++)
#pragma unroll
    for (int ni = 0; ni < 4; ni++) acc[mi][ni] = (f32x4){0.f, 0.f, 0.f, 0.f};

  for (int k0 = 0; k0 < K; k0 += 32) {
    __syncthreads();  // previous iteration's frag reads must finish
#pragma unroll
    for (int i = 0; i < 2; i++) {
      const int f = (i * 256 + w * 64 + lane) * 8;  // element in 128x32 tile
      const int row = f >> 5, col = f & 31;
      bf16* ldsbase_a = sA + (i * 256 + w * 64) * 8;  // wave-uniform
      bf16* ldsbase_b = sB + (i * 256 + w * 64) * 8;
      gl2lds16(A + (size_t)(mBase + row) * K + k0 + col, ldsbase_a);
      gl2lds16(Bt + (size_t)(nBase + row) * K + k0 + col, ldsbase_b);
    }
    __syncthreads();  // drains vmcnt (global_load_lds) + makes LDS visible

    short8 af[4], bfg[4];
#pragma unroll
    for (int t = 0; t < 4; t++) {
      af[t] = *(const short8*)(sA + (wr * 64 + t * 16 + n16) * 32 + quad * 8);
      bfg[t] = *(const short8*)(sB + (wc * 64 + t * 16 + n16) * 32 + quad * 8);
    }
#pragma unroll
    for (int mi = 0; mi < 4; mi++)
#pragma unroll
      for (int ni = 0; ni < 4; ni++)
        acc[mi][ni] = MFMA16(af[mi], bfg[ni], acc[mi][ni]);
  }

  // Epilogue. C/D layout: col = lane&15, row = quad*4 + reg  [verified m89/m91]
#pragma unroll
  for (int mi = 0; mi < 4; mi++)
#pragma unroll
    for (int ni = 0; ni < 4; ni++)
#pragma unroll
      for (int r = 0; r < 4; r++) {
        const int row = mBase + wr * 64 + mi * 16 + quad * 4 + r;
        const int col = nBase + wc * 64 + ni * 16 + n16;
        const float v = acc[mi][ni][r] + bias[col];
        if (WRITE_BF16)
          outb[(size_t)row * N + col] = __float2bfloat16(v);
        else
          outf[(size_t)row * N + col] = v;
      }
}

// ---------------------------------------------------------------------------
// Flash attention v6 (512 threads / 8 waves; 256 q rows per block; exact
// 2 blocks/CU with zero tail rounds).  S^T = K·Q^T; double-buffered K/V
// tiles, ONE barrier per iter.  No-max softmax (scores bounded) is exact.
// relf fragment order (float4 idx): ((qt*32+kt)*8 + w)*512 + (mi*4+kt4)*64 +
//   lane; components = 4 consecutive keys, pre-scaled by log2e.
// ---------------------------------------------------------------------------
__global__ __launch_bounds__(512, 4) void flash_kernel(
    const bf16* __restrict__ qkv, const float* __restrict__ relf,
    bf16* __restrict__ attn) {
  constexpr int S = 2048, R3 = 3072;
  __shared__ bf16 sK[2][64 * 32 * 2];  // [buf][dchunk][key][32]  8 KB each
  __shared__ bf16 sVt[2][64 * 72];     // [buf][d][key] stride 72 9 KB each
  __shared__ bf16 sPT[8][32 * 72];     // per-wave [q][key]      36 KB

  const int tid = threadIdx.x, w = tid >> 6, lane = tid & 63;
  const int n16 = lane & 15, quad = lane >> 4;
  const int qt = blockIdx.x & 7;     // 8 q-tiles of 256
  const int bh = blockIdx.x >> 3;
  const int h = bh & 15, b = bh >> 4;
  const int qb = qt * 256 + w * 32;  // this wave's first q row (within S)
  const size_t rowbase = (size_t)b * S;
  const float SC = 0.125f * 1.44269504f;  // (1/sqrt(D)) * log2(e)
  const size_t TADV = (size_t)64 * R3;    // advance one key-tile

  // Q B-frags [mi][dchunk]: lane holds B[n=n16][k=quad*8+j]
  short8 qf[2][2];
#pragma unroll
  for (int mi = 0; mi < 2; mi++) {
    const bf16* qp = qkv + (rowbase + qb + mi * 16 + n16) * R3 + h * 64;
#pragma unroll
    for (int c = 0; c < 2; c++) qf[mi][c] = *(const short8*)(qp + c * 32 + quad * 8);
  }

  f32x4 ot[4][2];  // O^T accum: [d-tile nc][q-tile mi]; row=d, col=q
#pragma unroll
  for (int nc = 0; nc < 4; nc++)
#pragma unroll
    for (int mi = 0; mi < 2; mi++) ot[nc][mi] = (f32x4){0.f, 0.f, 0.f, 0.f};
  float l_lane[2] = {0.f, 0.f};

  // ---- K-DMA: 512 lanes x 16B cover one [2][64][32] tile exactly
  const int kdc = tid >> 8, kkey = (tid >> 2) & 63, kdcol = (tid & 3) * 8;
  const bf16* kg =
      qkv + (rowbase + kkey) * R3 + 1024 + h * 64 + kdc * 32 + kdcol;
  const int kldsoff = w * 512;  // wave-uniform elem offset within buffer

  // ---- V staging: threads 0..255 -> (key pair kp, d octet); kp in low lane
  // bits keeps the b32 scatter conflict-free (banks = kp + 4*vd0).
  const int kp = tid & 31;            // keys 2kp, 2kp+1
  const int vd0 = ((tid >> 5) & 7) * 8;
  const bool vth = (tid < 256);
  const bf16* vp = qkv + (rowbase + 2 * kp) * R3 + 2048 + h * 64 + vd0;

  // ---- prologue: DMA K(0) -> sK[0]; V(0) -> sVt[0]; regs V(1), rel(0)
  gl2lds16(kg, &sK[0][kldsoff]);
  kg += TADV;  // -> tile 1

  short8 v0, v1;
  if (vth) {
    v0 = *(const short8*)vp;
    v1 = *(const short8*)(vp + R3);
    union { short8 s; unsigned int d[4]; } u0, u1;
    u0.s = v0; u1.s = v1;
#pragma unroll
    for (int m = 0; m < 4; m++) {
      *(unsigned int*)(&sVt[0][(vd0 + 2 * m) * 72 + 2 * kp]) =
          __builtin_amdgcn_perm(u1.d[m], u0.d[m], 0x05040100u);
      *(unsigned int*)(&sVt[0][(vd0 + 2 * m + 1) * 72 + 2 * kp]) =
          __builtin_amdgcn_perm(u1.d[m], u0.d[m], 0x07060302u);
    }
    vp += TADV;
    v0 = *(const short8*)vp;          // V(1) into regs
    v1 = *(const short8*)(vp + R3);
    vp += TADV;                       // -> tile 2
  }

  float4 rv[8];
  const float4* rp =
      (const float4*)relf + (size_t)(qt * 32) * 4096 + w * 512 + lane;
#pragma unroll
  for (int j = 0; j < 8; j++) rv[j] = rp[j * 64];
  rp += 4096;

  for (int kt = 0; kt < 32; kt++) {
    const int cur = kt & 1, nxt = cur ^ 1;
    __syncthreads();  // drains DMA(kt); V^T(kt) visible; prev readers done

    if (kt < 31) {
      // issue DMA K(kt+1) into other buffer; stage V^T(kt+1) from regs
      gl2lds16(kg, &sK[nxt][kldsoff]);
      kg += TADV;
      if (vth) {
        union { short8 s; unsigned int d[4]; } u0, u1;
        u0.s = v0; u1.s = v1;
#pragma unroll
        for (int m = 0; m < 4; m++) {
          *(unsigned int*)(&sVt[nxt][(vd0 + 2 * m) * 72 + 2 * kp]) =
              __builtin_amdgcn_perm(u1.d[m], u0.d[m], 0x05040100u);
          *(unsigned int*)(&sVt[nxt][(vd0 + 2 * m + 1) * 72 + 2 * kp]) =
              __builtin_amdgcn_perm(u1.d[m], u0.d[m], 0x07060302u);
        }
      }
    }

    // ---- S^T = K·Q^T: st[kt4][mi], row=key(quad*4+r), col=q(n16)
    f32x4 st[4][2];
#pragma unroll
    for (int kt4 = 0; kt4 < 4; kt4++) {
      short8 kf[2];
#pragma unroll
      for (int c = 0; c < 2; c++)
        kf[c] = *(const short8*)(&sK[cur][(c * 64 + kt4 * 16 + n16) * 32 + quad * 8]);
#pragma unroll
      for (int mi = 0; mi < 2; mi++) {
        f32x4 z = (f32x4){0.f, 0.f, 0.f, 0.f};
        z = MFMA16(kf[0], qf[mi][0], z);
        z = MFMA16(kf[1], qf[mi][1], z);
        st[kt4][mi] = z;
      }
    }
    // ---- prefetch V(kt+2) regs (hides under exp/PV)
    if (kt < 30 && vth) {
      v0 = *(const short8*)vp;
      v1 = *(const short8*)(vp + R3);
      vp += TADV;
    }
    // ---- p = 2^(s*SC + rel'), packed (truncating) b64 writes into sPT
#pragma unroll
    for (int mi = 0; mi < 2; mi++) {
      float acc = 0.f;
#pragma unroll
      for (int kt4 = 0; kt4 < 4; kt4++) {
        const float4 rr = rv[mi * 4 + kt4];
        float p[4];
        p[0] = __builtin_amdgcn_exp2f(fmaf(st[kt4][mi][0], SC, rr.x));
        p[1] = __builtin_amdgcn_exp2f(fmaf(st[kt4][mi][1], SC, rr.y));
        p[2] = __builtin_amdgcn_exp2f(fmaf(st[kt4][mi][2], SC, rr.z));
        p[3] = __builtin_amdgcn_exp2f(fmaf(st[kt4][mi][3], SC, rr.w));
        acc += (p[0] + p[1]) + (p[2] + p[3]);
        uint2 pk;
        pk.x = pkbf_t(p[0], p[1]);
        pk.y = pkbf_t(p[2], p[3]);
        *(uint2*)(&sPT[w][(mi * 16 + n16) * 72 + kt4 * 16 + quad * 4]) = pk;
      }
      l_lane[mi] += acc;
    }
    // ---- prefetch rel(kt+1) (rv dead; hides under PV)
    if (kt < 31) {
#pragma unroll
      for (int j = 0; j < 8; j++) rv[j] = rp[j * 64];
      rp += 4096;
    }
    // ---- PV: O^T += V^T · P^T  (wave-private sPT, in-order DS)
#pragma unroll
    for (int kc = 0; kc < 2; kc++) {
      short8 va[4], pb[2];
#pragma unroll
      for (int nc = 0; nc < 4; nc++)
        va[nc] = *(const short8*)(&sVt[cur][(nc * 16 + n16) * 72 + kc * 32 + quad * 8]);
#pragma unroll
      for (int mi = 0; mi < 2; mi++)
        pb[mi] = *(const short8*)(&sPT[w][(mi * 16 + n16) * 72 + kc * 32 + quad * 8]);
#pragma unroll
      for (int nc = 0; nc < 4; nc++)
#pragma unroll
        for (int mi = 0; mi < 2; mi++)
          ot[nc][mi] = MFMA16(va[nc], pb[mi], ot[nc][mi]);
    }
  }

  // ---- epilogue: l reduce over quads (lanes n16 / +16 / +32 / +48)
  float inv[2];
#pragma unroll
  for (int mi = 0; mi < 2; mi++) {
    float l = l_lane[mi];
    l += __shfl_xor(l, 16);
    l += __shfl_xor(l, 32);
    inv[mi] = 1.0f / l;
  }
  // transpose O^T -> [q][d] via wave-private LDS (packed b64 writes)
#pragma unroll
  for (int mi = 0; mi < 2; mi++)
#pragma unroll
    for (int nc = 0; nc < 4; nc++) {
      uint2 pk;
      pk.x = pkbf(ot[nc][mi][0] * inv[mi], ot[nc][mi][1] * inv[mi]);
      pk.y = pkbf(ot[nc][mi][2] * inv[mi], ot[nc][mi][3] * inv[mi]);
      *(uint2*)(&sPT[w][(mi * 16 + n16) * 72 + nc * 16 + quad * 4]) = pk;
    }
  // coalesced store: 32 rows x 64 d, 16B per lane
#pragma unroll
  for (int t = 0; t < 4; t++) {
    const int row = t * 8 + (lane >> 3);
    const int dcol = (lane & 7) * 8;
    const short8 vrow = *(const short8*)(&sPT[w][row * 72 + dcol]);
    *(short8*)(attn + (rowbase + qb + row) * 1024 + h * 64 + dcol) = vrow;
  }
}

// ---------------------------------------------------------------------------
// prep: fused weight cast + bias concat + x build (block ranges)
// ---------------------------------------------------------------------------
__global__ void prep_main(const float* __restrict__ fm, const float* __restrict__ scene,
                          const float* __restrict__ Wq, const float* __restrict__ Wk,
                          const float* __restrict__ Wv, const float* __restrict__ Wo,
                          const float* __restrict__ bq, const float* __restrict__ bk,
                          const float* __restrict__ bv, bf16* __restrict__ wW,
                          bf16* __restrict__ wWo, float* __restrict__ bC,
                          bf16* __restrict__ x) {
  const int blk = blockIdx.x;
  if (blk < 4096) {
    const int sel = blk >> 10;  // 0..3
    const int i = (((blk & 1023) * 256) + threadIdx.x) * 4;
    const float* src = (sel == 0) ? Wq : (sel == 1) ? Wk : (sel == 2) ? Wv : Wo;
    bf16* dst = (sel < 3) ? (wW + ((size_t)sel << 20) + i) : (wWo + i);
    const float4 v = *(const float4*)(src + i);
    dst[0] = __float2bfloat16(v.x);
    dst[1] = __float2bfloat16(v.y);
    dst[2] = __float2bfloat16(v.z);
    dst[3] = __float2bfloat16(v.w);
    if (blk == 0) {
      for (int z = threadIdx.x; z < 3072; z += 256)
        bC[z] = (z < 1024) ? bq[z] : (z < 2048) ? bk[z - 1024] : bv[z - 2048];
    }
  } else {
    const int bx = blk - 4096;
    const size_t i = ((size_t)bx * 256 + threadIdx.x) * 4;
    const int r = (int)(i >> 10), c = (int)(i & 1023);
    const int b = r >> 11, s = r & 2047;
    const float* src = (s < 1024)
                           ? (scene + ((size_t)b << 10) + c)
                           : (fm + (((size_t)b * 1024 + (s - 1024)) << 10) + c);
    const float4 v = *(const float4*)src;
    bf16* d = x + i;
    d[0] = __float2bfloat16(v.x);
    d[1] = __float2bfloat16(v.y);
    d[2] = __float2bfloat16(v.z);
    d[3] = __float2bfloat16(v.w);
  }
}

// rel -> S^T fragment-ordered relf (x log2e). One thread per output float4;
// components are 4 consecutive keys. Matches flash v6 (8 waves, qt in 0..7).
__global__ void prep_rel(const float* __restrict__ rel, float* __restrict__ relf) {
  const int idx = blockIdx.x * 256 + threadIdx.x;  // 0 .. 2^20-1
  const int lane = idx & 63;
  const int j = (idx >> 6) & 7;     // mi*4 + kt4
  const int w = (idx >> 9) & 7;
  const int kt = (idx >> 12) & 31;
  const int qt = idx >> 17;
  const int n16 = lane & 15, quad = lane >> 4;
  const int mi = j >> 2, kt4 = j & 3;
  const int qrow = qt * 256 + w * 32 + mi * 16 + n16;
  const int key = kt * 64 + kt4 * 16 + quad * 4;
  const float L2E = 1.44269504f;
  float4 v = *(const float4*)(rel + (size_t)qrow * 2048 + key);
  v.x *= L2E; v.y *= L2E; v.z *= L2E; v.w *= L2E;
  ((float4*)relf)[idx] = v;
}

// ---------------------------------------------------------------------------
extern "C" void kernel_launch(void* const* d_in, const int* in_sizes, int n_in,
                              void* d_out, int out_size, void* d_ws,
                              size_t ws_size, hipStream_t stream) {
  const float* fm    = (const float*)d_in[0];
  const float* scene = (const float*)d_in[1];
  const float* rel   = (const float*)d_in[2];
  const float* Wq    = (const float*)d_in[3];
  const float* bq    = (const float*)d_in[4];
  const float* Wk    = (const float*)d_in[5];
  const float* bk    = (const float*)d_in[6];
  const float* Wv    = (const float*)d_in[7];
  const float* bv    = (const float*)d_in[8];
  const float* Wo    = (const float*)d_in[9];
  const float* bo    = (const float*)d_in[10];
  float* out = (float*)d_out;

  char* ws = (char*)d_ws;
  bf16* x    = (bf16*)(ws);                          // 16 MB  [8192,1024]
  float* relf = (float*)(ws);                        // 16 MB  (aliases x; x dead after QKV GEMM)
  bf16* qkv  = (bf16*)(ws + (16u << 20));            // 48 MB  [8192,3072]
  bf16* attn = (bf16*)(ws + (64u << 20));            // 16 MB  [8192,1024]
  bf16* wW   = (bf16*)(ws + (80u << 20));            // 6 MB   [3072,1024] Wq|Wk|Wv rows
  bf16* wWo  = (bf16*)(ws + (86u << 20));            // 2 MB   [1024,1024]
  float* bC  = (float*)(ws + (88u << 20));           // 12 KB  bq|bk|bv

  prep_main<<<12288, 256, 0, stream>>>(fm, scene, Wq, Wk, Wv, Wo, bq, bk, bv,
                                       wW, wWo, bC, x);

  // QKV fused: [8192,1024] @ [3072,1024]^T + bC -> [8192,3072] bf16
  gemm_bt<1><<<dim3(24, 64), 256, 0, stream>>>(x, wW, bC, qkv, nullptr,
                                               8192, 3072, 1024);
  // x is dead now; build fragment-ordered rel into the same region
  prep_rel<<<4096, 256, 0, stream>>>(rel, relf);
  // attention: B*H*(S/256) = 4*16*8 = 512 blocks, 512 threads (8 waves)
  flash_kernel<<<512, 512, 0, stream>>>(qkv, relf, attn);
  // output projection: [8192,1024] @ [1024,1024]^T + bo -> f32 out
  gemm_bt<0><<<dim3(8, 64), 256, 0, stream>>>(attn, wWo, bo, nullptr, out,
                                              8192, 1024, 1024);
}

// Round 7
// 351.754 us; speedup vs baseline: 1.2864x; 1.2864x over previous
//
#include <hip/hip_runtime.h>
#include <hip/hip_bf16.h>
#include <cstdint>

// Problem constants: B=4, N=1024, F=1024, H=16, D=64, S=2N=2048.
typedef __hip_bfloat16 bf16;
typedef __attribute__((ext_vector_type(8))) short short8;   // 8 x bf16 (4 VGPRs)
typedef __attribute__((ext_vector_type(4))) float f32x4;

#define MFMA16(a, b, c) __builtin_amdgcn_mfma_f32_16x16x32_bf16((a), (b), (c), 0, 0, 0)

__device__ __forceinline__ void gl2lds16(const void* g, void* l) {
  // async global->LDS, 16B/lane; LDS dest = wave-uniform base + lane*16
  __builtin_amdgcn_global_load_lds(
      (const __attribute__((address_space(1))) unsigned int*)g,
      (__attribute__((address_space(3))) unsigned int*)l,
      16, 0, 0);
}

// pack two f32 -> bf16x2, round-half-up (3 VALU: add, add, v_perm)
__device__ __forceinline__ unsigned int pkbf(float a, float b) {
  const unsigned int ua = __builtin_bit_cast(unsigned int, a) + 0x8000u;
  const unsigned int ub = __builtin_bit_cast(unsigned int, b) + 0x8000u;
  return __builtin_amdgcn_perm(ub, ua, 0x07060302u);
}
// truncating pack (1 VALU op); p>=0 and l stays exact fp32 -> bias harmless
__device__ __forceinline__ unsigned int pkbf_t(float a, float b) {
  return __builtin_amdgcn_perm(__builtin_bit_cast(unsigned int, b),
                               __builtin_bit_cast(unsigned int, a), 0x07060302u);
}

// ---------------------------------------------------------------------------
// GEMM  C = A @ Bt^T + bias.  128x128 tile, BK=32, 256 thr, 16x16x32 MFMA.
// MODE 0: fp32 out to outf[row*N+col]            (o-projection)
// MODE 1: QKV split: cols<2048 -> bf16 qkvQK[row*2048+col];
//         cols>=2048 (V) -> bf16 vT[(b*1024+hd)*2048 + key], keys packed 4/lane
//         with key-octet XOR swizzle ((hd&7)*8) baked in for conflict-free
//         LDS DMA+frag reads in flash.
// ---------------------------------------------------------------------------
template <int MODE>
__global__ __launch_bounds__(256) void gemm_bt(
    const bf16* __restrict__ A, const bf16* __restrict__ Bt,
    const float* __restrict__ bias, bf16* __restrict__ outb,
    float* __restrict__ outf, bf16* __restrict__ vt, int M, int N, int K) {
  __shared__ bf16 sA[128 * 32];
  __shared__ bf16 sB[128 * 32];
  const int tid = threadIdx.x, w = tid >> 6, lane = tid & 63;
  const int n16 = lane & 15, quad = lane >> 4;
  const int mBase = blockIdx.y * 128, nBase = blockIdx.x * 128;
  const int wr = w >> 1, wc = w & 1;

  f32x4 acc[4][4];
#pragma unroll
  for (int mi = 0; mi < 4; mi++)
#pragma unroll
    for (int ni = 0; ni < 4; ni++) acc[mi][ni] = (f32x4){0.f, 0.f, 0.f, 0.f};

  for (int k0 = 0; k0 < K; k0 += 32) {
    __syncthreads();
#pragma unroll
    for (int i = 0; i < 2; i++) {
      const int f = (i * 256 + w * 64 + lane) * 8;
      const int row = f >> 5, col = f & 31;
      bf16* ldsbase_a = sA + (i * 256 + w * 64) * 8;
      bf16* ldsbase_b = sB + (i * 256 + w * 64) * 8;
      gl2lds16(A + (size_t)(mBase + row) * K + k0 + col, ldsbase_a);
      gl2lds16(Bt + (size_t)(nBase + row) * K + k0 + col, ldsbase_b);
    }
    __syncthreads();

    short8 af[4], bfg[4];
#pragma unroll
    for (int t = 0; t < 4; t++) {
      af[t] = *(const short8*)(sA + (wr * 64 + t * 16 + n16) * 32 + quad * 8);
      bfg[t] = *(const short8*)(sB + (wc * 64 + t * 16 + n16) * 32 + quad * 8);
    }
#pragma unroll
    for (int mi = 0; mi < 4; mi++)
#pragma unroll
      for (int ni = 0; ni < 4; ni++)
        acc[mi][ni] = MFMA16(af[mi], bfg[ni], acc[mi][ni]);
  }

  // Epilogue. C/D layout: col = lane&15, row = quad*4 + reg  [m89/m91]
  if (MODE == 0) {
#pragma unroll
    for (int mi = 0; mi < 4; mi++)
#pragma unroll
      for (int ni = 0; ni < 4; ni++)
#pragma unroll
        for (int r = 0; r < 4; r++) {
          const int row = mBase + wr * 64 + mi * 16 + quad * 4 + r;
          const int col = nBase + wc * 64 + ni * 16 + n16;
          outf[(size_t)row * N + col] = acc[mi][ni][r] + bias[col];
        }
  } else if (nBase < 2048) {
    // Q/K columns -> qkvQK, row stride 2048
#pragma unroll
    for (int mi = 0; mi < 4; mi++)
#pragma unroll
      for (int ni = 0; ni < 4; ni++)
#pragma unroll
        for (int r = 0; r < 4; r++) {
          const int row = mBase + wr * 64 + mi * 16 + quad * 4 + r;
          const int col = nBase + wc * 64 + ni * 16 + n16;
          outb[(size_t)row * 2048 + col] = __float2bfloat16(acc[mi][ni][r] + bias[col]);
        }
  } else {
    // V columns -> transposed + swizzled vT
    const int rowb = mBase + wr * 64;         // 64-aligned
    const int b = rowb >> 11;
    const int keybase = rowb & 2047;          // 64-aligned
#pragma unroll
    for (int ni = 0; ni < 4; ni++) {
      const int cv = nBase - 2048 + wc * 64 + ni * 16 + n16;  // hd index
      const float bs = bias[nBase + wc * 64 + ni * 16 + n16];
      bf16* vrow = vt + (((size_t)(b * 1024 + cv)) << 11) + keybase;
#pragma unroll
      for (int mi = 0; mi < 4; mi++) {
        const int off6 = (mi * 16 + quad * 4) ^ ((cv & 7) * 8);
        uint2 pk;
        pk.x = pkbf(acc[mi][ni][0] + bs, acc[mi][ni][1] + bs);
        pk.y = pkbf(acc[mi][ni][2] + bs, acc[mi][ni][3] + bs);
        *(uint2*)(vrow + off6) = pk;
      }
    }
  }
}

// ---------------------------------------------------------------------------
// Flash attention v7:
//   256 thr / 4 waves, 128 q rows/block, 64-key tiles, S^T = K·Q^T.
//   K AND V both staged by pure global_load_lds DMA (V pre-transposed+swizzled
//   by the QKV GEMM).  Double-buffered sK/sVt, ONE barrier per iter.
//   sPT kc-split (32 keys at a time) with XOR-8-block swizzle -> 2 KB/wave.
//   LDS total = 16 + 16 + 8 = 40960 B exactly -> 4 blocks/CU, grid 1024 =
//   4/CU with zero tail.  No-max softmax (scores bounded) is exact.
// ---------------------------------------------------------------------------
__global__ __launch_bounds__(256) void flash_kernel(
    const bf16* __restrict__ qk, const bf16* __restrict__ vt,
    const float* __restrict__ relf, bf16* __restrict__ attn) {
  constexpr int S = 2048, R2 = 2048;
  __shared__ __align__(16) char smem[40960];
  bf16* sK = (bf16*)smem;             // [2][4096] : [buf][c][key][32]
  bf16* sVt = (bf16*)(smem + 16384);  // [2][4096] : [buf][d][key^swz]
  bf16* sPT = (bf16*)(smem + 32768);  // [4][1024] : per-wave [32 q][32 key] swz

  const int tid = threadIdx.x, w = tid >> 6, lane = tid & 63;
  const int n16 = lane & 15, quad = lane >> 4;
  const int qt = blockIdx.x & 15;
  const int bh = blockIdx.x >> 4;
  const int h = bh & 15, b = bh >> 4;
  const int qb = qt * 128 + w * 32;
  const size_t rowbase = (size_t)b * S;
  const float SC = 0.125f * 1.44269504f;
  const size_t TADVK = (size_t)64 * R2;

  // Q B-frags [mi][dchunk]
  short8 qf[2][2];
#pragma unroll
  for (int mi = 0; mi < 2; mi++) {
    const bf16* qp = qk + (rowbase + qb + mi * 16 + n16) * R2 + h * 64;
#pragma unroll
    for (int c = 0; c < 2; c++) qf[mi][c] = *(const short8*)(qp + c * 32 + quad * 8);
  }

  f32x4 ot[4][2];  // O^T accum: [d-tile nc][q-tile mi]
#pragma unroll
  for (int nc = 0; nc < 4; nc++)
#pragma unroll
    for (int mi = 0; mi < 2; mi++) ot[nc][mi] = (f32x4){0.f, 0.f, 0.f, 0.f};
  float l_lane[2] = {0.f, 0.f};

  // K-DMA source pointers (tile 0)
  const bf16* kg[2];
#pragma unroll
  for (int i = 0; i < 2; i++) {
    const int f = (i * 256 + tid) * 8;
    const int c = f >> 11, key = (f >> 5) & 63, dcol = f & 31;
    kg[i] = qk + (rowbase + key) * R2 + 1024 + h * 64 + c * 32 + dcol;
  }
  // V-DMA source pointers (tile 0): image [d][64 keys(swizzled)]
  const bf16* vg[2];
#pragma unroll
  for (int i = 0; i < 2; i++) {
    const int d = (i * 256 + tid) >> 3;
    vg[i] = vt + (((size_t)(b * 1024 + h * 64 + d)) << 11) + (tid & 7) * 8;
  }
  const int ldsoff = w * 512;  // + i*2048 within buffer (elems)

  // prologue: DMA K(0), V(0) into buf 0; rel(0) into regs
#pragma unroll
  for (int i = 0; i < 2; i++) {
    gl2lds16(kg[i], sK + ldsoff + i * 2048);
    gl2lds16(vg[i], sVt + ldsoff + i * 2048);
    kg[i] += TADVK;
    vg[i] += 64;
  }
  float4 rv[8];
  const float4* rp = (const float4*)relf + (size_t)(qt * 32) * 2048 + w * 512 + lane;
#pragma unroll
  for (int j = 0; j < 8; j++) rv[j] = rp[j * 64];
  rp += 2048;

  for (int kt = 0; kt < 32; kt++) {
    const int cur = kt & 1, nxt = cur ^ 1;
    __syncthreads();  // drains DMA(kt); prev readers done

    if (kt < 31) {
#pragma unroll
      for (int i = 0; i < 2; i++) {
        gl2lds16(kg[i], sK + nxt * 4096 + ldsoff + i * 2048);
        gl2lds16(vg[i], sVt + nxt * 4096 + ldsoff + i * 2048);
        kg[i] += TADVK;
        vg[i] += 64;
      }
    }

    // ---- S^T = K·Q^T: st[kt4][mi], row=key(quad*4+r), col=q(n16)
    f32x4 st[4][2];
#pragma unroll
    for (int kt4 = 0; kt4 < 4; kt4++) {
      short8 kf[2];
#pragma unroll
      for (int c = 0; c < 2; c++)
        kf[c] = *(const short8*)(sK + cur * 4096 + (c * 64 + kt4 * 16 + n16) * 32 + quad * 8);
#pragma unroll
      for (int mi = 0; mi < 2; mi++) {
        f32x4 z = (f32x4){0.f, 0.f, 0.f, 0.f};
        z = MFMA16(kf[0], qf[mi][0], z);
        z = MFMA16(kf[1], qf[mi][1], z);
        st[kt4][mi] = z;
      }
    }

    // ---- kc-split: exp 32 keys -> sPT (swizzled), then PV those 32 keys
    bf16* myP = sPT + w * 1024;
#pragma unroll
    for (int kc = 0; kc < 2; kc++) {
#pragma unroll
      for (int mi = 0; mi < 2; mi++) {
        const int row = mi * 16 + n16;
        float acc = 0.f;
#pragma unroll
        for (int k2 = 0; k2 < 2; k2++) {
          const int kt4 = kc * 2 + k2;
          const float4 rr = rv[mi * 4 + kt4];
          float p[4];
          p[0] = __builtin_amdgcn_exp2f(fmaf(st[kt4][mi][0], SC, rr.x));
          p[1] = __builtin_amdgcn_exp2f(fmaf(st[kt4][mi][1], SC, rr.y));
          p[2] = __builtin_amdgcn_exp2f(fmaf(st[kt4][mi][2], SC, rr.z));
          p[3] = __builtin_amdgcn_exp2f(fmaf(st[kt4][mi][3], SC, rr.w));
          acc += (p[0] + p[1]) + (p[2] + p[3]);
          // col = k2*16 + quad*4; 8-block swizzle: blk' = blk ^ (row&3)
          const int blk = k2 * 2 + (quad >> 1);
          const int eoff = row * 32 + ((blk ^ (row & 3)) * 8) + (quad & 1) * 4;
          uint2 pk;
          pk.x = pkbf_t(p[0], p[1]);
          pk.y = pkbf_t(p[2], p[3]);
          *(uint2*)(myP + eoff) = pk;
        }
        l_lane[mi] += acc;
      }
      // PV for these 32 keys
      short8 va[4], pb[2];
#pragma unroll
      for (int nc = 0; nc < 4; nc++) {
        const int d = nc * 16 + n16;
        const int voff = (kc * 32 + quad * 8) ^ ((d & 7) * 8);
        va[nc] = *(const short8*)(sVt + cur * 4096 + d * 64 + voff);
      }
#pragma unroll
      for (int mi = 0; mi < 2; mi++) {
        const int row = mi * 16 + n16;
        pb[mi] = *(const short8*)(myP + row * 32 + ((quad ^ (row & 3)) * 8));
      }
#pragma unroll
      for (int nc = 0; nc < 4; nc++)
#pragma unroll
        for (int mi = 0; mi < 2; mi++)
          ot[nc][mi] = MFMA16(va[nc], pb[mi], ot[nc][mi]);
    }

    // ---- prefetch rel(kt+1)
    if (kt < 31) {
#pragma unroll
      for (int j = 0; j < 8; j++) rv[j] = rp[j * 64];
      rp += 2048;
    }
  }

  // ---- epilogue: l reduce over quads
  float inv[2];
#pragma unroll
  for (int mi = 0; mi < 2; mi++) {
    float l = l_lane[mi];
    l += __shfl_xor(l, 16);
    l += __shfl_xor(l, 32);
    inv[mi] = 1.0f / l;
  }
  __syncthreads();  // all waves done with sK/sVt; reuse as epilogue buffers
  bf16* eb = (bf16*)smem + w * 2304;  // [32 q][72] per wave (18.4KB <= 32KB)
#pragma unroll
  for (int mi = 0; mi < 2; mi++)
#pragma unroll
    for (int nc = 0; nc < 4; nc++) {
      uint2 pk;
      pk.x = pkbf(ot[nc][mi][0] * inv[mi], ot[nc][mi][1] * inv[mi]);
      pk.y = pkbf(ot[nc][mi][2] * inv[mi], ot[nc][mi][3] * inv[mi]);
      *(uint2*)(eb + (mi * 16 + n16) * 72 + nc * 16 + quad * 4) = pk;
    }
#pragma unroll
  for (int t = 0; t < 4; t++) {
    const int row = t * 8 + (lane >> 3);
    const int dcol = (lane & 7) * 8;
    const short8 vrow = *(const short8*)(eb + row * 72 + dcol);
    *(short8*)(attn + (rowbase + qb + row) * 1024 + h * 64 + dcol) = vrow;
  }
}

// ---------------------------------------------------------------------------
// prep: fused weight cast + bias concat + x build
// ---------------------------------------------------------------------------
__global__ void prep_main(const float* __restrict__ fm, const float* __restrict__ scene,
                          const float* __restrict__ Wq, const float* __restrict__ Wk,
                          const float* __restrict__ Wv, const float* __restrict__ Wo,
                          const float* __restrict__ bq, const float* __restrict__ bk,
                          const float* __restrict__ bv, bf16* __restrict__ wW,
                          bf16* __restrict__ wWo, float* __restrict__ bC,
                          bf16* __restrict__ x) {
  const int blk = blockIdx.x;
  if (blk < 4096) {
    const int sel = blk >> 10;
    const int i = (((blk & 1023) * 256) + threadIdx.x) * 4;
    const float* src = (sel == 0) ? Wq : (sel == 1) ? Wk : (sel == 2) ? Wv : Wo;
    bf16* dst = (sel < 3) ? (wW + ((size_t)sel << 20) + i) : (wWo + i);
    const float4 v = *(const float4*)(src + i);
    dst[0] = __float2bfloat16(v.x);
    dst[1] = __float2bfloat16(v.y);
    dst[2] = __float2bfloat16(v.z);
    dst[3] = __float2bfloat16(v.w);
    if (blk == 0) {
      for (int z = threadIdx.x; z < 3072; z += 256)
        bC[z] = (z < 1024) ? bq[z] : (z < 2048) ? bk[z - 1024] : bv[z - 2048];
    }
  } else {
    const int bx = blk - 4096;
    const size_t i = ((size_t)bx * 256 + threadIdx.x) * 4;
    const int r = (int)(i >> 10), c = (int)(i & 1023);
    const int b = r >> 11, s = r & 2047;
    const float* src = (s < 1024)
                           ? (scene + ((size_t)b << 10) + c)
                           : (fm + (((size_t)b * 1024 + (s - 1024)) << 10) + c);
    const float4 v = *(const float4*)src;
    bf16* d = x + i;
    d[0] = __float2bfloat16(v.x);
    d[1] = __float2bfloat16(v.y);
    d[2] = __float2bfloat16(v.z);
    d[3] = __float2bfloat16(v.w);
  }
}

// rel -> S^T fragment-ordered relf (x log2e); components = 4 consecutive keys.
// Matches flash v7 (4 waves, qt 0..15).
__global__ void prep_rel(const float* __restrict__ rel, float* __restrict__ relf) {
  const int idx = blockIdx.x * 256 + threadIdx.x;  // 0 .. 2^20-1
  const int lane = idx & 63;
  const int j = (idx >> 6) & 7;     // mi*4 + kt4
  const int w = (idx >> 9) & 3;
  const int kt = (idx >> 11) & 31;
  const int qt = idx >> 16;
  const int n16 = lane & 15, quad = lane >> 4;
  const int mi = j >> 2, kt4 = j & 3;
  const int qrow = qt * 128 + w * 32 + mi * 16 + n16;
  const int key = kt * 64 + kt4 * 16 + quad * 4;
  const float L2E = 1.44269504f;
  float4 v = *(const float4*)(rel + (size_t)qrow * 2048 + key);
  v.x *= L2E; v.y *= L2E; v.z *= L2E; v.w *= L2E;
  ((float4*)relf)[idx] = v;
}

// ---------------------------------------------------------------------------
extern "C" void kernel_launch(void* const* d_in, const int* in_sizes, int n_in,
                              void* d_out, int out_size, void* d_ws,
                              size_t ws_size, hipStream_t stream) {
  const float* fm    = (const float*)d_in[0];
  const float* scene = (const float*)d_in[1];
  const float* rel   = (const float*)d_in[2];
  const float* Wq    = (const float*)d_in[3];
  const float* bq    = (const float*)d_in[4];
  const float* Wk    = (const float*)d_in[5];
  const float* bk    = (const float*)d_in[6];
  const float* Wv    = (const float*)d_in[7];
  const float* bv    = (const float*)d_in[8];
  const float* Wo    = (const float*)d_in[9];
  const float* bo    = (const float*)d_in[10];
  float* out = (float*)d_out;

  char* ws = (char*)d_ws;
  bf16* x     = (bf16*)(ws);                // 16 MB [8192,1024]; relf aliases after QKV
  float* relf = (float*)(ws);
  bf16* qkQK  = (bf16*)(ws + (16u << 20));  // 32 MB [8192,2048] Q|K
  bf16* vT    = (bf16*)(ws + (48u << 20));  // 16 MB [4096 hd][2048 key] swizzled
  bf16* attn  = (bf16*)(ws + (64u << 20));  // 16 MB [8192,1024]
  bf16* wW    = (bf16*)(ws + (80u << 20));  // 6 MB  [3072,1024]
  bf16* wWo   = (bf16*)(ws + (86u << 20));  // 2 MB  [1024,1024]
  float* bC   = (float*)(ws + (88u << 20)); // 12 KB

  prep_main<<<12288, 256, 0, stream>>>(fm, scene, Wq, Wk, Wv, Wo, bq, bk, bv,
                                       wW, wWo, bC, x);

  // QKV fused: Q,K -> qkQK; V -> transposed+swizzled vT
  gemm_bt<1><<<dim3(24, 64), 256, 0, stream>>>(x, wW, bC, qkQK, nullptr, vT,
                                               8192, 3072, 1024);
  prep_rel<<<4096, 256, 0, stream>>>(rel, relf);
  // attention: 4*16*16 = 1024 blocks, 256 threads, 4 blocks/CU exact
  flash_kernel<<<1024, 256, 0, stream>>>(qkQK, vT, relf, attn);
  // output projection
  gemm_bt<0><<<dim3(8, 64), 256, 0, stream>>>(attn, wWo, bo, nullptr, out,
                                              nullptr, 8192, 1024, 1024);
}